// Round 2
// baseline (864.686 us; speedup 1.0000x reference)
//
#include <hip/hip_runtime.h>
#include <math.h>

#define BATCH 16
#define EMB   32
#define HW    262144          // 512*512
#define NL    3

#define BLOCKS_PER_IMG 128
#define PX_PER_BLOCK   (HW / BLOCKS_PER_IMG)          // 2048
#define WAVES_PER_BLK  4
#define PX_PER_WAVE    (PX_PER_BLOCK / WAVES_PER_BLK) // 512
#define TILE_PX        32                             // pixels per wave-iter
#define N_ITERS        (PX_PER_WAVE / TILE_PX)        // 16

// ---- workspace layout (floats) ----
#define WS_COUNTS 0                     // BATCH*4
#define WS_SE     64                    // BATCH*96  sum_emb[b][l][e]
#define WS_SH     (WS_SE + BATCH*96)    // BATCH*96  sum_hat[b][l][e]
#define WS_CE     (WS_SH + BATCH*96)    // 1
#define WS_FLOATS (WS_CE + 1)

__device__ __forceinline__ float ce1(float a, float b, float c, int l) {
    const float m = fmaxf(fmaxf(a, b), c);
    const float s = __expf(a - m) + __expf(b - m) + __expf(c - m);
    const float zl = (l == 0) ? a : ((l == 1) ? b : c);
    return m + __logf(s) - zl;
}

// ============================================================================
// Fused kernel, wave-independent version (no LDS, no __syncthreads).
// Lane layout within a wave: lane = cg*8 + ps   (cg 0..7 channel-group,
// ps 0..7 pixel-slot). Thread owns channels cg*4..cg*4+3 x pixels ps*4..ps*4+3
// of a 32-pixel tile. Per-pixel ||emb|| reduction = 3 x __shfl_xor (8,16,32)
// entirely inside the wave -> waves run free, latency hidden by occupancy.
// CE handled by the channel-group cg == (it & 7) for that iteration's tile.
// ============================================================================
__global__ __launch_bounds__(256) void fused_kernel(
        const float* __restrict__ emb, const float* __restrict__ pred,
        const int* __restrict__ label, float* __restrict__ ws)
{
    const int tid  = threadIdx.x;
    const int lane = tid & 63;
    const int wv   = tid >> 6;         // wave 0..3
    const int ps   = lane & 7;         // pixel-slot 0..7
    const int cg   = lane >> 3;        // channel-group 0..7
    const int b    = blockIdx.x / BLOCKS_PER_IMG;
    const int blk  = blockIdx.x % BLOCKS_PER_IMG;

    const float* embB  = emb   + (size_t)b * EMB * HW;
    const float* predB = pred  + (size_t)b * 3 * HW;
    const int*   labB  = label + (size_t)b * HW;

    const size_t base = (size_t)blk * PX_PER_BLOCK
                      + (size_t)wv * PX_PER_WAVE
                      + (size_t)ps * 4;

    const float* ch0 = embB + (size_t)(cg*4+0)*HW + base;
    const float* ch1 = embB + (size_t)(cg*4+1)*HW + base;
    const float* ch2 = embB + (size_t)(cg*4+2)*HW + base;
    const float* ch3 = embB + (size_t)(cg*4+3)*HW + base;
    const int*   lb  = labB + base;
    const float* pr  = predB + base;

    float accE[NL][4] = {};    // sum_emb  [label][k]
    float accH[2][4]  = {};    // sum_hat  [label-1][k]  (labels 1,2 only; sh[0] unused)
    float cnt0 = 0.f, cnt1 = 0.f, cnt2 = 0.f;
    float ce = 0.f;

    for (int it = 0; it < N_ITERS; ++it) {
        const size_t off = (size_t)it * TILE_PX;

        const float4 v0 = *(const float4*)(ch0 + off);
        const float4 v1 = *(const float4*)(ch1 + off);
        const float4 v2 = *(const float4*)(ch2 + off);
        const float4 v3 = *(const float4*)(ch3 + off);
        const int4  lab = *(const int4*)(lb + off);

        const bool doCE = (cg == (it & 7));
        float4 z0, z1, z2;
        if (doCE) {
            z0 = *(const float4*)(pr + off);
            z1 = *(const float4*)(pr + HW + off);
            z2 = *(const float4*)(pr + 2*HW + off);
        }

        // ---- per-pixel sum of squares over this thread's 4 channels ----
        float4 s;
        s.x = v0.x*v0.x + v1.x*v1.x + v2.x*v2.x + v3.x*v3.x;
        s.y = v0.y*v0.y + v1.y*v1.y + v2.y*v2.y + v3.y*v3.y;
        s.z = v0.z*v0.z + v1.z*v1.z + v2.z*v2.z + v3.z*v3.z;
        s.w = v0.w*v0.w + v1.w*v1.w + v2.w*v2.w + v3.w*v3.w;
        // reduce across the 8 channel-groups: lane bits 3,4,5
        s.x += __shfl_xor(s.x, 8);  s.x += __shfl_xor(s.x, 16);  s.x += __shfl_xor(s.x, 32);
        s.y += __shfl_xor(s.y, 8);  s.y += __shfl_xor(s.y, 16);  s.y += __shfl_xor(s.y, 32);
        s.z += __shfl_xor(s.z, 8);  s.z += __shfl_xor(s.z, 16);  s.z += __shfl_xor(s.z, 32);
        s.w += __shfl_xor(s.w, 8);  s.w += __shfl_xor(s.w, 16);  s.w += __shfl_xor(s.w, 32);

        float invn[4];
        invn[0] = 1.0f / fmaxf(sqrtf(s.x), 1e-8f);
        invn[1] = 1.0f / fmaxf(sqrtf(s.y), 1e-8f);
        invn[2] = 1.0f / fmaxf(sqrtf(s.z), 1e-8f);
        invn[3] = 1.0f / fmaxf(sqrtf(s.w), 1e-8f);

        const float chv[4][4] = {   // [pixel j][channel k]
            {v0.x, v1.x, v2.x, v3.x},
            {v0.y, v1.y, v2.y, v3.y},
            {v0.z, v1.z, v2.z, v3.z},
            {v0.w, v1.w, v2.w, v3.w}};
        const int labs[4] = {lab.x, lab.y, lab.z, lab.w};

        #pragma unroll
        for (int j = 0; j < 4; ++j) {
            const float m0 = (labs[j] == 0) ? 1.f : 0.f;
            const float m1 = (labs[j] == 1) ? 1.f : 0.f;
            const float m2 = (labs[j] == 2) ? 1.f : 0.f;
            const float iv = invn[j];
            if (cg == 0) { cnt0 += m0; cnt1 += m1; cnt2 += m2; }
            #pragma unroll
            for (int k = 0; k < 4; ++k) {
                const float v  = chv[j][k];
                const float vh = v * iv;
                accE[0][k] = fmaf(m0, v,  accE[0][k]);
                accE[1][k] = fmaf(m1, v,  accE[1][k]);
                accE[2][k] = fmaf(m2, v,  accE[2][k]);
                accH[0][k] = fmaf(m1, vh, accH[0][k]);
                accH[1][k] = fmaf(m2, vh, accH[1][k]);
            }
        }

        if (doCE) {
            ce += ce1(z0.x, z1.x, z2.x, labs[0]);
            ce += ce1(z0.y, z1.y, z2.y, labs[1]);
            ce += ce1(z0.z, z1.z, z2.z, labs[2]);
            ce += ce1(z0.w, z1.w, z2.w, labs[3]);
        }
    }

    // ---- reduce over the 8 pixel-slots within each channel-group octet ----
    #pragma unroll
    for (int o = 4; o >= 1; o >>= 1) {
        #pragma unroll
        for (int l = 0; l < NL; ++l)
            #pragma unroll
            for (int k = 0; k < 4; ++k)
                accE[l][k] += __shfl_xor(accE[l][k], o);
        #pragma unroll
        for (int l = 0; l < 2; ++l)
            #pragma unroll
            for (int k = 0; k < 4; ++k)
                accH[l][k] += __shfl_xor(accH[l][k], o);
        cnt0 += __shfl_xor(cnt0, o);
        cnt1 += __shfl_xor(cnt1, o);
        cnt2 += __shfl_xor(cnt2, o);
    }
    // ce lives scattered across all lanes (cg rotation): full butterfly
    #pragma unroll
    for (int o = 32; o >= 1; o >>= 1) ce += __shfl_xor(ce, o);

    if (ps == 0) {
        float* se = ws + WS_SE + b * 96;
        float* sh = ws + WS_SH + b * 96;
        #pragma unroll
        for (int l = 0; l < NL; ++l)
            #pragma unroll
            for (int k = 0; k < 4; ++k)
                atomicAdd(&se[l*32 + cg*4 + k], accE[l][k]);
        #pragma unroll
        for (int l = 0; l < 2; ++l)
            #pragma unroll
            for (int k = 0; k < 4; ++k)
                atomicAdd(&sh[(l+1)*32 + cg*4 + k], accH[l][k]);
    }
    if (lane == 0) {
        atomicAdd(&ws[WS_CE], ce * (1.0f / (float)HW));
        atomicAdd(&ws[WS_COUNTS + b*4 + 0], cnt0);
        atomicAdd(&ws[WS_COUNTS + b*4 + 1], cnt1);
        atomicAdd(&ws[WS_COUNTS + b*4 + 2], cnt2);
    }
}

// ============================================================================
// Finalize. Block 512 = 16 images x 32 channels.
// ============================================================================
__global__ __launch_bounds__(512) void final_kernel(
        const int* __restrict__ nbr, const float* __restrict__ ws,
        float* __restrict__ out)
{
    const int tid = threadIdx.x;
    const int b = tid >> 5;
    const int e = tid & 31;
    __shared__ float total;
    if (tid == 0) total = 0.f;
    __syncthreads();

    const float* se = ws + WS_SE + b * 96;
    const float* sh = ws + WS_SH + b * 96;
    const float c0 = ws[WS_COUNTS + b*4 + 0];
    const float c1 = ws[WS_COUNTS + b*4 + 1];
    const float c2 = ws[WS_COUNTS + b*4 + 2];

    float mean0 = se[0*32 + e] / c0;
    float mean1 = se[1*32 + e] / c1;
    float mean2 = se[2*32 + e] / c2;

    float n0 = mean0*mean0, n1 = mean1*mean1, n2 = mean2*mean2;
    #pragma unroll
    for (int o = 16; o >= 1; o >>= 1) {
        n0 += __shfl_xor(n0, o);
        n1 += __shfl_xor(n1, o);
        n2 += __shfl_xor(n2, o);
    }
    const float nm0 = mean0 / fmaxf(sqrtf(n0), 1e-12f);
    const float nm1 = mean1 / fmaxf(sqrtf(n1), 1e-12f);
    const float nm2 = mean2 / fmaxf(sqrtf(n2), 1e-12f);

    float d1  = nm1 * sh[1*32 + e];
    float d2  = nm2 * sh[2*32 + e];
    float s10 = nm1 * nm0, s11 = nm1 * nm1, s12 = nm1 * nm2;
    float s20 = nm2 * nm0, s21 = nm2 * nm1, s22 = nm2 * nm2;
    #pragma unroll
    for (int o = 16; o >= 1; o >>= 1) {
        d1  += __shfl_xor(d1, o);  d2  += __shfl_xor(d2, o);
        s10 += __shfl_xor(s10, o); s11 += __shfl_xor(s11, o); s12 += __shfl_xor(s12, o);
        s20 += __shfl_xor(s20, o); s21 += __shfl_xor(s21, o); s22 += __shfl_xor(s22, o);
    }

    if (e == 0) {
        float S[3][3];
        S[1][0] = s10; S[1][1] = s11; S[1][2] = s12;
        S[2][0] = s20; S[2][1] = s21; S[2][2] = s22;
        S[0][0] = S[0][1] = S[0][2] = 0.f;
        float mask[3][3] = {{0.f,0.f,0.f},{0.f,0.f,0.f},{0.f,0.f,0.f}};
        for (int row = 1; row < 3; ++row) {
            int prod = 1;
            for (int j = 0; j < 3; ++j) {
                const int v = nbr[b*9 + row*3 + j];
                if (v == 0) prod = 0;           // cumprod includes current elem
                if (prod) mask[row][v] = 1.f;   // scatter-max
            }
        }
        float num = 0.f, den = 0.f;
        for (int row = 1; row < 3; ++row)
            for (int col = 0; col < 3; ++col) {
                num += S[row][col] * mask[row][col];
                den += mask[row][col];
            }
        const float inter = num / den;
        const float ip1 = 1.f - d1 / c1;
        const float ip2 = 1.f - d2 / c2;
        const float loss = 0.5f * (ip1 + ip2) + inter;
        atomicAdd(&total, loss);
    }
    __syncthreads();
    if (tid == 0) out[0] = total + ws[WS_CE];
}

// ============================================================================
extern "C" void kernel_launch(void* const* d_in, const int* in_sizes, int n_in,
                              void* d_out, int out_size, void* d_ws, size_t ws_size,
                              hipStream_t stream) {
    const float* emb   = (const float*)d_in[0];
    const float* pred  = (const float*)d_in[1];
    const int*   label = (const int*)d_in[2];
    const int*   nbr   = (const int*)d_in[3];
    float* ws  = (float*)d_ws;
    float* out = (float*)d_out;

    hipMemsetAsync(d_ws, 0, WS_FLOATS * sizeof(float), stream);
    fused_kernel<<<BATCH * BLOCKS_PER_IMG, 256, 0, stream>>>(emb, pred, label, ws);
    final_kernel<<<1, 512, 0, stream>>>(nbr, ws, out);
}